// Round 3
// baseline (589.519 us; speedup 1.0000x reference)
//
#include <hip/hip_runtime.h>

#define INV_QTR 0.59460355750136053f   // 8^(-1/4)

typedef _Float16 f16;
typedef _Float16 f16x8 __attribute__((ext_vector_type(8)));
typedef float f32x4 __attribute__((ext_vector_type(4)));

// Load 8 consecutive fp32 elements and convert to f16x8.
__device__ __forceinline__ f16x8 load_cvt8(const float* p) {
    const f32x4* q = (const f32x4*)p;
    f32x4 a = q[0], b = q[1];
    f16x8 r;
    #pragma unroll
    for (int j = 0; j < 4; ++j) { r[j] = (f16)a[j]; r[j + 4] = (f16)b[j]; }
    return r;
}

// ---------------------------------------------------------------------------
// BT-GEMM: dst[m][n] = sum_k X[m][k]*W[n][k] (+bias[n]). M=16384,N=1024,K=1024.
// 128x128 tile, BK=64, register staging -> ds_write_b128, XOR swizzle on 16B
// chunks, 16x16x32 f16 MFMA, fp32 accum.
// XF: X is fp32 (else f16). OF: output fp32 (else f16). BIAS: add fp32 bias.
// ---------------------------------------------------------------------------
template <bool XF, bool OF, bool BIAS>
__device__ __forceinline__ void gemm_bt_body(const void* __restrict__ X,
                                             const float* __restrict__ W,
                                             const float* __restrict__ bias,
                                             void* __restrict__ dst) {
    __shared__ __align__(16) f16 As[128 * 64];
    __shared__ __align__(16) f16 Bs[128 * 64];

    const int tid  = threadIdx.x;
    const int lane = tid & 63;
    const int wave = tid >> 6;
    const int m0   = blockIdx.x * 128;
    const int n0   = blockIdx.y * 128;
    const int wm   = (wave >> 1) * 64;
    const int wn   = (wave & 1) * 64;
    const int frow = lane & 15;
    const int quad = lane >> 4;

    f32x4 acc[4][4] = {};

    for (int k0 = 0; k0 < 1024; k0 += 64) {
        f16x8 stA[4], stB[4];
        #pragma unroll
        for (int i = 0; i < 4; ++i) {
            int slot = i * 256 + tid;         // row*8 + chunk
            int row  = slot >> 3;
            int sc   = slot & 7;
            int gc   = sc ^ (row & 7);        // XOR swizzle (involution)
            size_t ax = (size_t)(m0 + row) * 1024 + k0 + gc * 8;
            if (XF) stA[i] = load_cvt8((const float*)X + ax);
            else    stA[i] = *(const f16x8*)((const f16*)X + ax);
            stB[i] = load_cvt8(W + (size_t)(n0 + row) * 1024 + k0 + gc * 8);
        }
        __syncthreads();   // prior iteration's LDS readers done
        #pragma unroll
        for (int i = 0; i < 4; ++i) {
            int slot = i * 256 + tid;
            *(f16x8*)(As + slot * 8) = stA[i];
            *(f16x8*)(Bs + slot * 8) = stB[i];
        }
        __syncthreads();   // staging visible

        #pragma unroll
        for (int kk = 0; kk < 2; ++kk) {
            f16x8 fa[4], fb[4];
            #pragma unroll
            for (int t = 0; t < 4; ++t) {
                int arow = wm + t * 16 + frow;
                int asc  = (kk * 4 + quad) ^ (arow & 7);
                fa[t] = *(const f16x8*)(As + arow * 64 + asc * 8);
                int brow = wn + t * 16 + frow;
                int bsc  = (kk * 4 + quad) ^ (brow & 7);
                fb[t] = *(const f16x8*)(Bs + brow * 64 + bsc * 8);
            }
            #pragma unroll
            for (int tm = 0; tm < 4; ++tm)
                #pragma unroll
                for (int tn = 0; tn < 4; ++tn)
                    acc[tm][tn] = __builtin_amdgcn_mfma_f32_16x16x32_f16(
                        fa[tm], fb[tn], acc[tm][tn], 0, 0, 0);
        }
    }

    // C/D layout: col=lane&15, row=quad*4+reg (verified m89/m91, dtype-indep)
    #pragma unroll
    for (int tn = 0; tn < 4; ++tn) {
        int col = n0 + wn + tn * 16 + frow;
        float badd = BIAS ? bias[col] : 0.0f;
        #pragma unroll
        for (int tm = 0; tm < 4; ++tm) {
            #pragma unroll
            for (int r = 0; r < 4; ++r) {
                size_t idx = (size_t)(m0 + wm + tm * 16 + quad * 4 + r) * 1024 + col;
                float v = acc[tm][tn][r] + badd;
                if (OF) ((float*)dst)[idx] = v;
                else    ((f16*)dst)[idx] = (f16)v;
            }
        }
    }
}

// grid (128, 8, 3): z picks q/k/v projection. fp32 in, f16 out.
__global__ void qkv_gemm(const float* __restrict__ q, const float* __restrict__ k,
                         const float* __restrict__ v,
                         const float* __restrict__ Wq, const float* __restrict__ bq,
                         const float* __restrict__ Wk, const float* __restrict__ bk,
                         const float* __restrict__ Wv, const float* __restrict__ bv,
                         f16* __restrict__ qp, f16* __restrict__ kp,
                         f16* __restrict__ vp) {
    int z = blockIdx.z;
    const float* X = (z == 0) ? q : (z == 1) ? k : v;
    const float* W = (z == 0) ? Wq : (z == 1) ? Wk : Wv;
    const float* bias = (z == 0) ? bq : (z == 1) ? bk : bv;
    f16* dst = (z == 0) ? qp : (z == 1) ? kp : vp;
    gemm_bt_body<true, false, true>(X, W, bias, dst);
}

// grid (128, 8): out = att @ Wo^T (no bias). f16 att, fp32 Wo, fp32 out.
__global__ void out_gemm(const f16* __restrict__ att, const float* __restrict__ Wo,
                         float* __restrict__ out) {
    gemm_bt_body<false, true, false>(att, Wo, nullptr, out);
}

// ---------------------------------------------------------------------------
// qs = softmax(qp over 64-wide head group) * INV_QTR, in place (f16 buffer).
// ---------------------------------------------------------------------------
__global__ void q_softmax(f16* __restrict__ qp) {
    int gid  = blockIdx.x * 4 + (threadIdx.x >> 6);
    int lane = threadIdx.x & 63;
    size_t off = (size_t)gid * 64 + lane;
    float x = (float)qp[off];
    float m = x;
    #pragma unroll
    for (int s = 32; s; s >>= 1) m = fmaxf(m, __shfl_xor(m, s, 64));
    float e = __expf(x - m);
    float sum = e;
    #pragma unroll
    for (int s = 32; s; s >>= 1) sum += __shfl_xor(sum, s, 64);
    qp[off] = (f16)(e / sum * INV_QTR);
}

// ---------------------------------------------------------------------------
// ctx stage 1: partial K^T V. grid (8 slices, 64 bh), block 256.
// part[slice][bh][d][e] fp32.
// ---------------------------------------------------------------------------
__global__ void ctx_partial(const f16* __restrict__ kp, const f16* __restrict__ vp,
                            float* __restrict__ part) {
    int slice = blockIdx.x, bh = blockIdx.y;
    int b = bh >> 4, h = bh & 15;
    int tid = threadIdx.x, lane = tid & 63, wave = tid >> 6;
    __shared__ __align__(16) f16 kS[64 * 64];
    __shared__ __align__(16) f16 vS[64 * 64];

    const size_t base = ((size_t)b * 4096 + slice * 512) * 1024 + h * 64;
    const int dg = wave * 16;
    float acc[16] = {};

    for (int c = 0; c < 8; ++c) {
        f16x8 sk[2], sv[2];
        #pragma unroll
        for (int i = 0; i < 2; ++i) {
            int slot = i * 256 + tid, row = slot >> 3, ch = slot & 7;
            size_t g = base + (size_t)(c * 64 + row) * 1024 + ch * 8;
            sk[i] = *(const f16x8*)(kp + g);
            sv[i] = *(const f16x8*)(vp + g);
        }
        __syncthreads();
        #pragma unroll
        for (int i = 0; i < 2; ++i) {
            int slot = i * 256 + tid;
            *(f16x8*)(kS + slot * 8) = sk[i];
            *(f16x8*)(vS + slot * 8) = sv[i];
        }
        __syncthreads();
        #pragma unroll 4
        for (int n = 0; n < 64; ++n) {
            float vv = (float)vS[n * 64 + lane];
            f16x8 k0 = *(const f16x8*)(kS + n * 64 + dg);
            f16x8 k1 = *(const f16x8*)(kS + n * 64 + dg + 8);
            #pragma unroll
            for (int j = 0; j < 8; ++j) {
                acc[j]     += (float)k0[j] * vv;
                acc[8 + j] += (float)k1[j] * vv;
            }
        }
    }
    float* dst = part + ((size_t)(slice * 64 + bh) * 64 + dg) * 64 + lane;
    #pragma unroll
    for (int j = 0; j < 16; ++j) dst[j * 64] = acc[j];
}

// ---------------------------------------------------------------------------
// ctx stage 2: sum partials, softmax over d, store ctxT[bh][e][d] f16.
// ---------------------------------------------------------------------------
__global__ void ctx_softmax(const float* __restrict__ part, f16* __restrict__ ctxT) {
    int bh = blockIdx.x;
    int tid = threadIdx.x;
    __shared__ float cs[64 * 65];
    float a[16];
    #pragma unroll
    for (int j = 0; j < 16; ++j) a[j] = 0.f;
    for (int s = 0; s < 8; ++s) {
        const float* p = part + (size_t)(s * 64 + bh) * 4096;
        #pragma unroll
        for (int j = 0; j < 16; ++j) a[j] += p[j * 256 + tid];
    }
    #pragma unroll
    for (int j = 0; j < 16; ++j) {
        int f = j * 256 + tid;
        cs[(f >> 6) * 65 + (f & 63)] = a[j];
    }
    __syncthreads();
    int lane = tid & 63, wave = tid >> 6;   // lane = d
    #pragma unroll
    for (int i = 0; i < 16; ++i) {
        int e = wave * 16 + i;
        float x = cs[lane * 65 + e];
        float m = x;
        #pragma unroll
        for (int s2 = 32; s2; s2 >>= 1) m = fmaxf(m, __shfl_xor(m, s2, 64));
        float ex = __expf(x - m);
        float sum = ex;
        #pragma unroll
        for (int s2 = 32; s2; s2 >>= 1) sum += __shfl_xor(sum, s2, 64);
        ctxT[((size_t)bh * 64 + e) * 64 + lane] = (f16)(ex / sum * INV_QTR);
    }
}

// ---------------------------------------------------------------------------
// att = qs @ ctx per head (block-diagonal, K=64). grid (128, 8). All f16.
// ---------------------------------------------------------------------------
__global__ void att_gemm(const f16* __restrict__ qs, const f16* __restrict__ ctxT,
                         f16* __restrict__ att) {
    __shared__ __align__(16) f16 As[2][128 * 64];
    __shared__ __align__(16) f16 Bs[2][64 * 64];
    int tid = threadIdx.x, lane = tid & 63, wave = tid >> 6;
    int m0 = blockIdx.x * 128;
    int n0 = blockIdx.y * 128;
    int b  = m0 >> 12;
    int h0 = (n0 >> 6) & 15;

    #pragma unroll
    for (int ch = 0; ch < 2; ++ch) {
        #pragma unroll
        for (int i = 0; i < 4; ++i) {
            int slot = i * 256 + tid, row = slot >> 3, sc = slot & 7, gc = sc ^ (row & 7);
            *(f16x8*)(As[ch] + slot * 8) =
                *(const f16x8*)(qs + (size_t)(m0 + row) * 1024 + n0 + ch * 64 + gc * 8);
        }
        #pragma unroll
        for (int i = 0; i < 2; ++i) {
            int slot = i * 256 + tid, row = slot >> 3, sc = slot & 7, gc = sc ^ (row & 7);
            int bh = b * 16 + h0 + ch;
            *(f16x8*)(Bs[ch] + slot * 8) =
                *(const f16x8*)(ctxT + ((size_t)bh * 64 + row) * 64 + gc * 8);
        }
    }
    __syncthreads();

    int wm = (wave >> 1) * 64, wn = wave & 1;
    int frow = lane & 15, quad = lane >> 4;
    f32x4 acc[4][4] = {};
    #pragma unroll
    for (int kk = 0; kk < 2; ++kk) {
        f16x8 fa[4], fb[4];
        #pragma unroll
        for (int t = 0; t < 4; ++t) {
            int arow = wm + t * 16 + frow;
            int asc  = (kk * 4 + quad) ^ (arow & 7);
            fa[t] = *(const f16x8*)(As[wn] + arow * 64 + asc * 8);
            int brow = t * 16 + frow;
            int bsc  = (kk * 4 + quad) ^ (brow & 7);
            fb[t] = *(const f16x8*)(Bs[wn] + brow * 64 + bsc * 8);
        }
        #pragma unroll
        for (int tm = 0; tm < 4; ++tm)
            #pragma unroll
            for (int tn = 0; tn < 4; ++tn)
                acc[tm][tn] = __builtin_amdgcn_mfma_f32_16x16x32_f16(
                    fa[tm], fb[tn], acc[tm][tn], 0, 0, 0);
    }
    #pragma unroll
    for (int tn = 0; tn < 4; ++tn) {
        int col = n0 + wn * 64 + tn * 16 + frow;
        #pragma unroll
        for (int tm = 0; tm < 4; ++tm) {
            #pragma unroll
            for (int r = 0; r < 4; ++r) {
                int row = m0 + wm + tm * 16 + quad * 4 + r;
                att[(size_t)row * 1024 + col] = (f16)acc[tm][tn][r];
            }
        }
    }
}

// ---------------------------------------------------------------------------
extern "C" void kernel_launch(void* const* d_in, const int* in_sizes, int n_in,
                              void* d_out, int out_size, void* d_ws, size_t ws_size,
                              hipStream_t stream) {
    const float* q  = (const float*)d_in[0];
    const float* k  = (const float*)d_in[1];
    const float* v  = (const float*)d_in[2];
    const float* Wq = (const float*)d_in[3];
    const float* bq = (const float*)d_in[4];
    const float* Wk = (const float*)d_in[5];
    const float* bk = (const float*)d_in[6];
    const float* Wv = (const float*)d_in[7];
    const float* bv = (const float*)d_in[8];
    const float* Wo = (const float*)d_in[9];

    char* ws = (char*)d_ws;
    f16*   qp   = (f16*)ws;                        // 32 MB (becomes qs in place)
    f16*   kp   = (f16*)(ws + 33554432);           // 32 MB (reused as att)
    float* part = (float*)(ws + 67108864);         // 8 MB
    f16*   ctxT = (f16*)(ws + 75497472);           // 0.5 MB
    f16*   vp   = (f16*)d_out;                     // vp scratch in d_out (64 MB fp32;
                                                   // vp dead before out_gemm writes)
    float* out  = (float*)d_out;

    qkv_gemm<<<dim3(128, 8, 3), 256, 0, stream>>>(q, k, v, Wq, bq, Wk, bk, Wv, bv,
                                                  qp, kp, vp);
    q_softmax<<<65536, 256, 0, stream>>>(qp);
    ctx_partial<<<dim3(8, 64), 256, 0, stream>>>(kp, vp, part);
    ctx_softmax<<<64, 256, 0, stream>>>(part, ctxT);
    att_gemm<<<dim3(128, 8), 256, 0, stream>>>(qp, ctxT, kp);    // att -> kp buffer
    out_gemm<<<dim3(128, 8), 256, 0, stream>>>(kp, Wo, out);
}

// Round 4
// 506.219 us; speedup vs baseline: 1.1646x; 1.1646x over previous
//
#include <hip/hip_runtime.h>

#define INV_QTR 0.59460355750136053f   // 8^(-1/4)

typedef _Float16 f16;
typedef _Float16 f16x8 __attribute__((ext_vector_type(8)));
typedef float f32x4 __attribute__((ext_vector_type(4)));

__device__ __forceinline__ void gload16(const void* g, void* l) {
    __builtin_amdgcn_global_load_lds(
        (const __attribute__((address_space(1))) void*)g,
        (__attribute__((address_space(3))) void*)l, 16, 0, 0);
}

// ---------------------------------------------------------------------------
// fp32 -> f16 conversion for q,k,v and the 4 weights (packed into Wh).
// 8 elems/thread; grid covers 3*16777216 + 4*1048576 = 54,525,952 elems exactly.
// ---------------------------------------------------------------------------
__global__ void cvt_all(const float* __restrict__ q, const float* __restrict__ k,
                        const float* __restrict__ v,
                        const float* __restrict__ Wq, const float* __restrict__ Wk,
                        const float* __restrict__ Wv, const float* __restrict__ Wo,
                        f16* __restrict__ qh, f16* __restrict__ kh,
                        f16* __restrict__ vh, f16* __restrict__ Wh) {
    const long long NX = 16777216;
    long long i = ((long long)blockIdx.x * 256 + threadIdx.x) * 8;
    const float* src;
    f16* dst;
    if (i < NX)            { src = q + i;            dst = qh + i; }
    else if (i < 2 * NX)   { src = k + (i - NX);     dst = kh + (i - NX); }
    else if (i < 3 * NX)   { src = v + (i - 2 * NX); dst = vh + (i - 2 * NX); }
    else {
        long long wi = i - 3 * NX;                   // 0 .. 4*1048576
        int wsel = (int)(wi >> 20);
        const float* ws = (wsel == 0) ? Wq : (wsel == 1) ? Wk : (wsel == 2) ? Wv : Wo;
        src = ws + (wi & 1048575);
        dst = Wh + wi;
    }
    f32x4 a = ((const f32x4*)src)[0];
    f32x4 b = ((const f32x4*)src)[1];
    f16x8 r;
    #pragma unroll
    for (int j = 0; j < 4; ++j) { r[j] = (f16)a[j]; r[j + 4] = (f16)b[j]; }
    *(f16x8*)dst = r;
}

// ---------------------------------------------------------------------------
// All-f16 BT-GEMM (m97 structure): dst[m][n] = sum_k X[m][k]*W[n][k] (+bias).
// M=16384, N=1024, K=1024. 128x128 tile, BK=64, global_load_lds width=16,
// XOR swizzle on 16B chunks, 16x16x32 f16 MFMA, fp32 accum.
// ---------------------------------------------------------------------------
template <bool OF, bool BIAS>
__device__ __forceinline__ void gemm_f16_body(const f16* __restrict__ X,
                                              const f16* __restrict__ W,
                                              const float* __restrict__ bias,
                                              void* __restrict__ dst) {
    __shared__ __align__(16) f16 As[128 * 64];
    __shared__ __align__(16) f16 Bs[128 * 64];

    const int tid  = threadIdx.x;
    const int lane = tid & 63;
    const int wave = tid >> 6;
    const int m0   = blockIdx.x * 128;
    const int n0   = blockIdx.y * 128;
    const int wm   = (wave >> 1) * 64;
    const int wn   = (wave & 1) * 64;
    const int frow = lane & 15;
    const int quad = lane >> 4;

    f32x4 acc[4][4] = {};

    for (int k0 = 0; k0 < 1024; k0 += 64) {
        __syncthreads();   // prior iteration's LDS readers done
        #pragma unroll
        for (int i = 0; i < 4; ++i) {
            int slot = i * 256 + tid;         // row*8 + chunk; consecutive per lane
            int row  = slot >> 3;
            int sc   = slot & 7;
            int gc   = sc ^ (row & 7);        // XOR swizzle (involution)
            gload16(X + (size_t)(m0 + row) * 1024 + k0 + gc * 8,
                    (char*)As + slot * 16);
            gload16(W + (size_t)(n0 + row) * 1024 + k0 + gc * 8,
                    (char*)Bs + slot * 16);
        }
        __syncthreads();   // vmcnt(0) drain: staging visible

        #pragma unroll
        for (int kk = 0; kk < 2; ++kk) {
            f16x8 fa[4], fb[4];
            #pragma unroll
            for (int t = 0; t < 4; ++t) {
                int arow = wm + t * 16 + frow;
                int asc  = (kk * 4 + quad) ^ (arow & 7);
                fa[t] = *(const f16x8*)(As + arow * 64 + asc * 8);
                int brow = wn + t * 16 + frow;
                int bsc  = (kk * 4 + quad) ^ (brow & 7);
                fb[t] = *(const f16x8*)(Bs + brow * 64 + bsc * 8);
            }
            #pragma unroll
            for (int tm = 0; tm < 4; ++tm)
                #pragma unroll
                for (int tn = 0; tn < 4; ++tn)
                    acc[tm][tn] = __builtin_amdgcn_mfma_f32_16x16x32_f16(
                        fa[tm], fb[tn], acc[tm][tn], 0, 0, 0);
        }
    }

    // C/D layout: col=lane&15, row=quad*4+reg (verified m89/m91, dtype-indep)
    #pragma unroll
    for (int tn = 0; tn < 4; ++tn) {
        int col = n0 + wn + tn * 16 + frow;
        float badd = BIAS ? bias[col] : 0.0f;
        #pragma unroll
        for (int tm = 0; tm < 4; ++tm) {
            #pragma unroll
            for (int r = 0; r < 4; ++r) {
                size_t idx = (size_t)(m0 + wm + tm * 16 + quad * 4 + r) * 1024 + col;
                float v = acc[tm][tn][r] + badd;
                if (OF) ((float*)dst)[idx] = v;
                else    ((f16*)dst)[idx] = (f16)v;
            }
        }
    }
}

// grid (128, 8): one projection, f16 in/out, fp32 bias.
__global__ void proj_gemm(const f16* __restrict__ X, const f16* __restrict__ W,
                          const float* __restrict__ bias, f16* __restrict__ dst) {
    gemm_f16_body<false, true>(X, W, bias, dst);
}

// grid (128, 8): out = att @ Wo^T (no bias), fp32 out.
__global__ void out_gemm(const f16* __restrict__ att, const f16* __restrict__ Wo,
                         float* __restrict__ out) {
    gemm_f16_body<true, false>(att, Wo, nullptr, out);
}

// ---------------------------------------------------------------------------
// qs = softmax(qp over 64-wide head group) * INV_QTR, in place (f16 buffer).
// ---------------------------------------------------------------------------
__global__ void q_softmax(f16* __restrict__ qp) {
    int gid  = blockIdx.x * 4 + (threadIdx.x >> 6);
    int lane = threadIdx.x & 63;
    size_t off = (size_t)gid * 64 + lane;
    float x = (float)qp[off];
    float m = x;
    #pragma unroll
    for (int s = 32; s; s >>= 1) m = fmaxf(m, __shfl_xor(m, s, 64));
    float e = __expf(x - m);
    float sum = e;
    #pragma unroll
    for (int s = 32; s; s >>= 1) sum += __shfl_xor(sum, s, 64);
    qp[off] = (f16)(e / sum * INV_QTR);
}

// ---------------------------------------------------------------------------
// ctx stage 1: partial K^T V. grid (8 slices, 64 bh), block 256.
// part[slice][bh][d][e] fp32.
// ---------------------------------------------------------------------------
__global__ void ctx_partial(const f16* __restrict__ kp, const f16* __restrict__ vp,
                            float* __restrict__ part) {
    int slice = blockIdx.x, bh = blockIdx.y;
    int b = bh >> 4, h = bh & 15;
    int tid = threadIdx.x, lane = tid & 63, wave = tid >> 6;
    __shared__ __align__(16) f16 kS[64 * 64];
    __shared__ __align__(16) f16 vS[64 * 64];

    const size_t base = ((size_t)b * 4096 + slice * 512) * 1024 + h * 64;
    const int dg = wave * 16;
    float acc[16] = {};

    for (int c = 0; c < 8; ++c) {
        __syncthreads();
        #pragma unroll
        for (int i = 0; i < 2; ++i) {
            int slot = i * 256 + tid, row = slot >> 3, ch = slot & 7;
            size_t g = base + (size_t)(c * 64 + row) * 1024 + ch * 8;
            gload16(kp + g, (char*)kS + slot * 16);
            gload16(vp + g, (char*)vS + slot * 16);
        }
        __syncthreads();
        #pragma unroll 4
        for (int n = 0; n < 64; ++n) {
            float vv = (float)vS[n * 64 + lane];
            f16x8 k0 = *(const f16x8*)(kS + n * 64 + dg);
            f16x8 k1 = *(const f16x8*)(kS + n * 64 + dg + 8);
            #pragma unroll
            for (int j = 0; j < 8; ++j) {
                acc[j]     += (float)k0[j] * vv;
                acc[8 + j] += (float)k1[j] * vv;
            }
        }
    }
    float* dst = part + ((size_t)(slice * 64 + bh) * 64 + dg) * 64 + lane;
    #pragma unroll
    for (int j = 0; j < 16; ++j) dst[j * 64] = acc[j];
}

// ---------------------------------------------------------------------------
// ctx stage 2: sum partials, softmax over d, store ctxT[bh][e][d] f16.
// ---------------------------------------------------------------------------
__global__ void ctx_softmax(const float* __restrict__ part, f16* __restrict__ ctxT) {
    int bh = blockIdx.x;
    int tid = threadIdx.x;
    __shared__ float cs[64 * 65];
    float a[16];
    #pragma unroll
    for (int j = 0; j < 16; ++j) a[j] = 0.f;
    for (int s = 0; s < 8; ++s) {
        const float* p = part + (size_t)(s * 64 + bh) * 4096;
        #pragma unroll
        for (int j = 0; j < 16; ++j) a[j] += p[j * 256 + tid];
    }
    #pragma unroll
    for (int j = 0; j < 16; ++j) {
        int f = j * 256 + tid;
        cs[(f >> 6) * 65 + (f & 63)] = a[j];
    }
    __syncthreads();
    int lane = tid & 63, wave = tid >> 6;   // lane = d
    #pragma unroll
    for (int i = 0; i < 16; ++i) {
        int e = wave * 16 + i;
        float x = cs[lane * 65 + e];
        float m = x;
        #pragma unroll
        for (int s2 = 32; s2; s2 >>= 1) m = fmaxf(m, __shfl_xor(m, s2, 64));
        float ex = __expf(x - m);
        float sum = ex;
        #pragma unroll
        for (int s2 = 32; s2; s2 >>= 1) sum += __shfl_xor(sum, s2, 64);
        ctxT[((size_t)bh * 64 + e) * 64 + lane] = (f16)(ex / sum * INV_QTR);
    }
}

// ---------------------------------------------------------------------------
// att = qs @ ctx per head (block-diagonal, K=64). grid (128, 8). All f16.
// ---------------------------------------------------------------------------
__global__ void att_gemm(const f16* __restrict__ qs, const f16* __restrict__ ctxT,
                         f16* __restrict__ att) {
    __shared__ __align__(16) f16 As[2][128 * 64];
    __shared__ __align__(16) f16 Bs[2][64 * 64];
    int tid = threadIdx.x, lane = tid & 63, wave = tid >> 6;
    int m0 = blockIdx.x * 128;
    int n0 = blockIdx.y * 128;
    int b  = m0 >> 12;
    int h0 = (n0 >> 6) & 15;

    #pragma unroll
    for (int ch = 0; ch < 2; ++ch) {
        #pragma unroll
        for (int i = 0; i < 4; ++i) {
            int slot = i * 256 + tid, row = slot >> 3, sc = slot & 7, gc = sc ^ (row & 7);
            gload16(qs + (size_t)(m0 + row) * 1024 + n0 + ch * 64 + gc * 8,
                    (char*)As[ch] + slot * 16);
        }
        #pragma unroll
        for (int i = 0; i < 2; ++i) {
            int slot = i * 256 + tid, row = slot >> 3, sc = slot & 7, gc = sc ^ (row & 7);
            int bh = b * 16 + h0 + ch;
            gload16(ctxT + ((size_t)bh * 64 + row) * 64 + gc * 8,
                    (char*)Bs[ch] + slot * 16);
        }
    }
    __syncthreads();

    int wm = (wave >> 1) * 64, wn = wave & 1;
    int frow = lane & 15, quad = lane >> 4;
    f32x4 acc[4][4] = {};
    #pragma unroll
    for (int kk = 0; kk < 2; ++kk) {
        f16x8 fa[4], fb[4];
        #pragma unroll
        for (int t = 0; t < 4; ++t) {
            int arow = wm + t * 16 + frow;
            int asc  = (kk * 4 + quad) ^ (arow & 7);
            fa[t] = *(const f16x8*)(As[wn] + arow * 64 + asc * 8);
            int brow = t * 16 + frow;
            int bsc  = (kk * 4 + quad) ^ (brow & 7);
            fb[t] = *(const f16x8*)(Bs[wn] + brow * 64 + bsc * 8);
        }
        #pragma unroll
        for (int tm = 0; tm < 4; ++tm)
            #pragma unroll
            for (int tn = 0; tn < 4; ++tn)
                acc[tm][tn] = __builtin_amdgcn_mfma_f32_16x16x32_f16(
                    fa[tm], fb[tn], acc[tm][tn], 0, 0, 0);
    }
    #pragma unroll
    for (int tn = 0; tn < 4; ++tn) {
        int col = n0 + wn * 64 + tn * 16 + frow;
        #pragma unroll
        for (int tm = 0; tm < 4; ++tm) {
            #pragma unroll
            for (int r = 0; r < 4; ++r) {
                int row = m0 + wm + tm * 16 + quad * 4 + r;
                att[(size_t)row * 1024 + col] = (f16)acc[tm][tn][r];
            }
        }
    }
}

// ---------------------------------------------------------------------------
// Buffer plan (all sizes bytes):
//   d_out (64 MB fp32): [qh 0..32M | kh 32M..64M] -> [kp | vp] -> final fp32 out
//   ws:  C   = ws+0        32M  vh -> part(8.4M) -> att
//        E   = ws+32M      32M  qp (becomes qs in place)
//        D   = ws+64M       8M  Wh = [Wq|Wk|Wv|Wo] f16
//        ctxT= ws+72M     256K
//   total 72M+256K <= known-good 76M.
// ---------------------------------------------------------------------------
extern "C" void kernel_launch(void* const* d_in, const int* in_sizes, int n_in,
                              void* d_out, int out_size, void* d_ws, size_t ws_size,
                              hipStream_t stream) {
    const float* q  = (const float*)d_in[0];
    const float* k  = (const float*)d_in[1];
    const float* v  = (const float*)d_in[2];
    const float* Wq = (const float*)d_in[3];
    const float* bq = (const float*)d_in[4];
    const float* Wk = (const float*)d_in[5];
    const float* bk = (const float*)d_in[6];
    const float* Wv = (const float*)d_in[7];
    const float* bv = (const float*)d_in[8];
    const float* Wo = (const float*)d_in[9];

    char* ws = (char*)d_ws;
    char* ob = (char*)d_out;
    f16*   vh   = (f16*)ws;                        // C
    float* part = (float*)ws;                      // C (after vh dead)
    f16*   att  = (f16*)ws;                        // C (after part dead)
    f16*   qp   = (f16*)(ws + 33554432);           // E
    f16*   Wh   = (f16*)(ws + 67108864);           // D: Wq|Wk|Wv|Wo f16
    f16*   ctxT = (f16*)(ws + 75497472);
    f16*   qh   = (f16*)ob;                        // d_out low half
    f16*   kh   = (f16*)(ob + 33554432);           // d_out high half
    f16*   kp   = (f16*)ob;                        // overwrites qh (dead)
    f16*   vp   = (f16*)(ob + 33554432);           // overwrites kh (dead)
    float* out  = (float*)d_out;

    cvt_all<<<26624, 256, 0, stream>>>(q, k, v, Wq, Wk, Wv, Wo, qh, kh, vh, Wh);
    proj_gemm<<<dim3(128, 8), 256, 0, stream>>>(qh, Wh,           bq, qp);
    proj_gemm<<<dim3(128, 8), 256, 0, stream>>>(kh, Wh + 1048576, bk, kp);
    proj_gemm<<<dim3(128, 8), 256, 0, stream>>>(vh, Wh + 2097152, bv, vp);
    q_softmax<<<65536, 256, 0, stream>>>(qp);
    ctx_partial<<<dim3(8, 64), 256, 0, stream>>>(kp, vp, part);
    ctx_softmax<<<64, 256, 0, stream>>>(part, ctxT);
    att_gemm<<<dim3(128, 8), 256, 0, stream>>>(qp, ctxT, att);
    out_gemm<<<dim3(128, 8), 256, 0, stream>>>(att, Wh + 3145728, out);
}